// Round 1
// baseline (40.250 us; speedup 1.0000x reference)
//
#include <hip/hip_runtime.h>

#define NUM_NODES   100000
#define NUM_EXPERTS 8
#define FEAT        128
#define NUM_RANKED  10000
#define NBLOCKS     256

// Per-node decomposition:
//   pair-sum = 0.5 * [ (E-1) * SA - Sum_d( Sw[d]*Slp[d] - Swlp[d] ) ]
// where per row e (after ranking gather): p = softmax, lp = log_softmax, w = exp(p)
//   SA  = Sum_{e,d} w*p,  Sw[d] = Sum_e w,  Slp[d] = Sum_e lp,  Swlp[d] = Sum_e w*lp
__global__ __launch_bounds__(256) void ecl_main(const float* __restrict__ xo,
                                               const int* __restrict__ rankings,
                                               const int* __restrict__ nodes,
                                               double* __restrict__ partial) {
  const int lane = threadIdx.x & 63;
  const int wid  = (blockIdx.x * blockDim.x + threadIdx.x) >> 6;
  const int nw   = (gridDim.x * blockDim.x) >> 6;

  double acc = 0.0;
  for (int s = wid; s < NUM_RANKED; s += nw) {
    const int node = nodes[s];
    const float* base = xo + (size_t)node * (NUM_EXPERTS * FEAT);

    float sa = 0.f;
    float sw0 = 0.f, sw1 = 0.f;
    float slp0 = 0.f, slp1 = 0.f;
    float swlp0 = 0.f, swlp1 = 0.f;

#pragma unroll
    for (int e = 0; e < NUM_EXPERTS; ++e) {
      const int r = rankings[s * NUM_EXPERTS + e];
      const float2 v = *reinterpret_cast<const float2*>(base + r * FEAT + lane * 2);

      // row max over 128 elems (2 per lane, 64 lanes)
      float m = fmaxf(v.x, v.y);
#pragma unroll
      for (int o = 32; o >= 1; o >>= 1) m = fmaxf(m, __shfl_xor(m, o));

      const float e0 = __expf(v.x - m);
      const float e1 = __expf(v.y - m);
      float ssum = e0 + e1;
#pragma unroll
      for (int o = 32; o >= 1; o >>= 1) ssum += __shfl_xor(ssum, o);

      const float inv = 1.0f / ssum;
      const float lse = __logf(ssum);
      const float lp0 = v.x - m - lse;
      const float lp1 = v.y - m - lse;
      const float p0 = e0 * inv;
      const float p1 = e1 * inv;
      const float w0 = __expf(p0);
      const float w1 = __expf(p1);

      sa    += w0 * p0 + w1 * p1;
      sw0   += w0;        sw1   += w1;
      slp0  += lp0;       slp1  += lp1;
      swlp0 += w0 * lp0;  swlp1 += w1 * lp1;
    }

    // per-lane share of (E-1)*SA - cross; reduce over wave
    float val = 7.0f * sa - (sw0 * slp0 - swlp0 + sw1 * slp1 - swlp1);
#pragma unroll
    for (int o = 32; o >= 1; o >>= 1) val += __shfl_xor(val, o);

    acc += 0.5 * (double)val;
  }

  __shared__ double lds[4];
  if (lane == 0) lds[threadIdx.x >> 6] = acc;
  __syncthreads();
  if (threadIdx.x == 0)
    partial[blockIdx.x] = lds[0] + lds[1] + lds[2] + lds[3];
}

__global__ __launch_bounds__(256) void ecl_reduce(const double* __restrict__ partial,
                                                  float* __restrict__ out) {
  __shared__ double lds[256];
  double a = 0.0;
  for (int i = threadIdx.x; i < NBLOCKS; i += 256) a += partial[i];
  lds[threadIdx.x] = a;
  __syncthreads();
  for (int s = 128; s >= 1; s >>= 1) {
    if (threadIdx.x < s) lds[threadIdx.x] += lds[threadIdx.x + s];
    __syncthreads();
  }
  if (threadIdx.x == 0) {
    const double scale = 0.1 / ((double)NUM_RANKED * 28.0);  // BETA / (S * P)
    out[0] = (float)(lds[0] * scale);
  }
}

extern "C" void kernel_launch(void* const* d_in, const int* in_sizes, int n_in,
                              void* d_out, int out_size, void* d_ws, size_t ws_size,
                              hipStream_t stream) {
  const float* expert_outputs = (const float*)d_in[0];
  const int*   rankings       = (const int*)d_in[1];
  const int*   node_indices   = (const int*)d_in[2];
  float* out = (float*)d_out;
  double* partial = (double*)d_ws;

  ecl_main<<<NBLOCKS, 256, 0, stream>>>(expert_outputs, rankings, node_indices, partial);
  ecl_reduce<<<1, 256, 0, stream>>>(partial, out);
}

// Round 2
// 30.687 us; speedup vs baseline: 1.3117x; 1.3117x over previous
//
#include <hip/hip_runtime.h>

#define NUM_NODES   100000
#define NUM_EXPERTS 8
#define FEAT        128
#define NUM_RANKED  10000
#define NBLOCKS     2500   // 4 waves/block * 2500 = 10000 waves = 1 per node

// Per-node decomposition (S = ranked nodes, P = 28 pairs):
//   pair-sum = 0.5 * [ (E-1) * SA - Sum_d( Sw[d]*Slp[d] - Swlp[d] ) ]
// with per gathered row e: p = softmax, lp = log_softmax, w = exp(p)
//   SA = Sum_{e,d} w*p,  Sw[d] = Sum_e w,  Slp[d] = Sum_e lp,  Swlp[d] = Sum_e w*lp
// Layout: one wave per node; lane holds dims {2*lane, 2*lane+1} of ALL 8 rows,
// so the cross-row sums are per-lane scalars (no cross-lane traffic until the end).
__global__ __launch_bounds__(256) void ecl_main(const float* __restrict__ xo,
                                               const int* __restrict__ rankings,
                                               const int* __restrict__ nodes,
                                               double* __restrict__ partial) {
  const int lane = threadIdx.x & 63;
  const int s    = (blockIdx.x * blockDim.x + threadIdx.x) >> 6;  // node slot, exact

  const int node = nodes[s];
  const float* base = xo + (size_t)node * (NUM_EXPERTS * FEAT);

  // batch-load the 8 ranking indices (uniform address -> cache broadcast)
  const int4 ra = *reinterpret_cast<const int4*>(rankings + s * NUM_EXPERTS);
  const int4 rb = *reinterpret_cast<const int4*>(rankings + s * NUM_EXPERTS + 4);
  const int r[8] = {ra.x, ra.y, ra.z, ra.w, rb.x, rb.y, rb.z, rb.w};

  // batch-issue all 8 gathered row loads (independent -> single waitcnt)
  float2 v[8];
#pragma unroll
  for (int e = 0; e < NUM_EXPERTS; ++e)
    v[e] = *reinterpret_cast<const float2*>(base + r[e] * FEAT + lane * 2);

  // 8 interleaved max-reduction chains (independent -> shuffle latency pipelines)
  float m[8];
#pragma unroll
  for (int e = 0; e < NUM_EXPERTS; ++e) m[e] = fmaxf(v[e].x, v[e].y);
#pragma unroll
  for (int o = 32; o >= 1; o >>= 1) {
#pragma unroll
    for (int e = 0; e < NUM_EXPERTS; ++e) m[e] = fmaxf(m[e], __shfl_xor(m[e], o));
  }

  float e0[8], e1[8], ssum[8];
#pragma unroll
  for (int e = 0; e < NUM_EXPERTS; ++e) {
    e0[e] = __expf(v[e].x - m[e]);
    e1[e] = __expf(v[e].y - m[e]);
    ssum[e] = e0[e] + e1[e];
  }
#pragma unroll
  for (int o = 32; o >= 1; o >>= 1) {
#pragma unroll
    for (int e = 0; e < NUM_EXPERTS; ++e) ssum[e] += __shfl_xor(ssum[e], o);
  }

  float sa = 0.f, sw0 = 0.f, sw1 = 0.f, slp0 = 0.f, slp1 = 0.f, swlp0 = 0.f, swlp1 = 0.f;
#pragma unroll
  for (int e = 0; e < NUM_EXPERTS; ++e) {
    const float inv = 1.0f / ssum[e];
    const float lse = __logf(ssum[e]);
    const float lp0 = v[e].x - m[e] - lse;
    const float lp1 = v[e].y - m[e] - lse;
    const float p0 = e0[e] * inv;
    const float p1 = e1[e] * inv;
    const float w0 = __expf(p0);
    const float w1 = __expf(p1);
    sa    += w0 * p0 + w1 * p1;
    sw0   += w0;        sw1   += w1;
    slp0  += lp0;       slp1  += lp1;
    swlp0 += w0 * lp0;  swlp1 += w1 * lp1;
  }

  float val = 7.0f * sa - (sw0 * slp0 - swlp0 + sw1 * slp1 - swlp1);
#pragma unroll
  for (int o = 32; o >= 1; o >>= 1) val += __shfl_xor(val, o);

  if (lane == 0) partial[s] = 0.5 * (double)val;
}

__global__ __launch_bounds__(256) void ecl_reduce(const double* __restrict__ partial,
                                                  float* __restrict__ out) {
  __shared__ double lds[256];
  double a = 0.0;
  for (int i = threadIdx.x; i < NUM_RANKED; i += 256) a += partial[i];
  lds[threadIdx.x] = a;
  __syncthreads();
  for (int s = 128; s >= 1; s >>= 1) {
    if (threadIdx.x < s) lds[threadIdx.x] += lds[threadIdx.x + s];
    __syncthreads();
  }
  if (threadIdx.x == 0) {
    const double scale = 0.1 / ((double)NUM_RANKED * 28.0);  // BETA / (S * P)
    out[0] = (float)(lds[0] * scale);
  }
}

extern "C" void kernel_launch(void* const* d_in, const int* in_sizes, int n_in,
                              void* d_out, int out_size, void* d_ws, size_t ws_size,
                              hipStream_t stream) {
  const float* expert_outputs = (const float*)d_in[0];
  const int*   rankings       = (const int*)d_in[1];
  const int*   node_indices   = (const int*)d_in[2];
  float* out = (float*)d_out;
  double* partial = (double*)d_ws;  // 10000 doubles = 80 KB (ws is ~1.6 GB)

  ecl_main<<<NBLOCKS, 256, 0, stream>>>(expert_outputs, rankings, node_indices, partial);
  ecl_reduce<<<1, 256, 0, stream>>>(partial, out);
}